// Round 1
// baseline (265.678 us; speedup 1.0000x reference)
//
#include <hip/hip_runtime.h>

// Problem: Embedding_6940667150787
//   idx:      [131072] int32 in [0, 198)
//   wordlist: [198, 512] float32
//   out:      [131072, 512] float32 = wordlist[idx] + positional_encoding
//
// PE: for j in 0..254: angle = i / 10000^(2j/512);
//     pe[i, 2j] = sin(angle), pe[i, 2j+1] = cos(angle); cols 510,511 = 0.
//
// R3 (this round):
//  - R=8 rows/thread (was 4): halves wave count, amortizes exp2/sincos setup,
//    idx loaded as two int4 vector loads.
//  - NON-TEMPORAL stores for the 268 MB output stream (never re-read; avoid
//    polluting/thrashing the 32 MB aggregate L2).
//  - last-column (cols 510,511) handled by zeroing (s1,c1) once before the
//    loop; the rotation recurrence keeps (0,0) at (0,0) -> no per-iter selects.

#define L_TOTAL 131072
#define VEC_PER_ROW 128   // 512 floats / 4
#define R 8               // rows per thread

typedef float f32x4 __attribute__((ext_vector_type(4)));
typedef int   i32x4 __attribute__((ext_vector_type(4)));

__device__ __forceinline__ void sincos_fast(float a, float& s, float& c) {
    // Cody-Waite reduction by 2*pi (FMA), then HW transcendental
    // (input in REVOLUTIONS).
    const float INV2PI = 0.15915493667125702f;
    const float PI2_HI = 6.2831854820251465f;
    const float PI2_LO = -1.7484555314695172e-7f;
    float k = rintf(a * INV2PI);               // exact in fp32 (k <= ~2.1e4)
    float r = fmaf(-k, PI2_HI, a);
    r = fmaf(-k, PI2_LO, r);                   // |r| <= pi, err ~4e-7 rad
    float rev = r * INV2PI;
    s = __builtin_amdgcn_sinf(rev);            // v_sin_f32: sin(rev*2pi)
    c = __builtin_amdgcn_cosf(rev);            // v_cos_f32
}

__global__ __launch_bounds__(256) void embed_pe_kernel(
    const int* __restrict__ idx,
    const float* __restrict__ wordlist,
    float* __restrict__ out)
{
    int t  = blockIdx.x * 256 + threadIdx.x;   // 0 .. (L/R)*128 - 1
    int rb = t >> 7;                           // row-block (R rows)
    int cc = t & 127;                          // float4 column
    int i0 = rb * R;

    // Inverse frequencies for pair j0=2cc (cols 4cc,4cc+1), j1=2cc+1.
    const float K = 0.051905126483205076f;     // log2(10000) / 256
    float invf0 = exp2f(-(float)(2 * cc)     * K);
    float invf1 = exp2f(-(float)(2 * cc + 1) * K);

    // Base-row sin/cos (full reduction) + per-row-step rotation.
    float s0, c0, s1, c1, sd0, cd0, sd1, cd1;
    sincos_fast((float)i0 * invf0, s0, c0);
    sincos_fast((float)i0 * invf1, s1, c1);
    sincos_fast(invf0, sd0, cd0);
    sincos_fast(invf1, sd1, cd1);

    // cols 510,511 must be PE=0. (0,0) is a fixed point of the rotation, so
    // zeroing once here suffices -- no per-iteration selects.
    if (cc == VEC_PER_ROW - 1) { s1 = 0.0f; c1 = 0.0f; }

    // Tokens for the 8 rows: two int4 vector loads (idx + rb*8, 32B-aligned).
    i32x4 ta = ((const i32x4*)idx)[rb * 2];
    i32x4 tb = ((const i32x4*)idx)[rb * 2 + 1];
    int tokens[R] = { ta[0], ta[1], ta[2], ta[3], tb[0], tb[1], tb[2], tb[3] };

    const f32x4* wl = (const f32x4*)wordlist;
    f32x4*       op = (f32x4*)out + (size_t)i0 * VEC_PER_ROW + cc;

#pragma unroll
    for (int k = 0; k < R; ++k) {
        f32x4 w = wl[tokens[k] * VEC_PER_ROW + cc];
        f32x4 o;
        o[0] = w[0] + s0;
        o[1] = w[1] + c0;
        o[2] = w[2] + s1;
        o[3] = w[3] + c1;
        __builtin_nontemporal_store(o, op + (size_t)k * VEC_PER_ROW);

        // rotate angles forward by one row: (s,c) <- angle + invf
        float ns0 = fmaf(s0, cd0, c0 * sd0);
        float nc0 = fmaf(c0, cd0, -s0 * sd0);
        s0 = ns0; c0 = nc0;
        float ns1 = fmaf(s1, cd1, c1 * sd1);
        float nc1 = fmaf(c1, cd1, -s1 * sd1);
        s1 = ns1; c1 = nc1;
    }
}

extern "C" void kernel_launch(void* const* d_in, const int* in_sizes, int n_in,
                              void* d_out, int out_size, void* d_ws, size_t ws_size,
                              hipStream_t stream) {
    const int*   idx      = (const int*)d_in[0];
    const float* wordlist = (const float*)d_in[1];
    float*       out      = (float*)d_out;

    int total_threads = (L_TOTAL / R) * VEC_PER_ROW;  // 2,097,152
    int block = 256;
    int grid = total_threads / block;                 // 8,192 blocks
    embed_pe_kernel<<<grid, block, 0, stream>>>(idx, wordlist, out);
}

// Round 2
// 254.855 us; speedup vs baseline: 1.0425x; 1.0425x over previous
//
#include <hip/hip_runtime.h>

// Problem: Embedding_6940667150787
//   idx:      [131072] int32 in [0, 198)
//   wordlist: [198, 512] float32
//   out:      [131072, 512] float32 = wordlist[idx] + positional_encoding
//
// PE: for j in 0..254: angle = i / 10000^(2j/512);
//     pe[i, 2j] = sin(angle), pe[i, 2j+1] = cos(angle); cols 510,511 = 0.
//
// R4 (this round):
//  - Reverted non-temporal stores -> plain stores. The harness's
//    fillBufferAligned sustains 6.4 TB/s with plain stores; nt coincided
//    with the 254.9 -> 265.7 regression.
//  - R=32 rows/thread (4 chunks x 8 rows): amortizes exp2/sincos setup and
//    idx-load latency over 4x more output; per extra row the rotation
//    recurrence costs only 8 FMA + 4 add + 1 load + 1 store.
//  - 2048 blocks x 256 threads = 8192 waves; low VGPR keeps full occupancy.
//  - Rotation chain is 32 steps: accumulated error ~3e-6, negligible vs the
//    already-accepted 0.03 absmax (freq ulp differences dominate).

#define L_TOTAL 131072
#define VEC_PER_ROW 128   // 512 floats / 4
#define R 32              // rows per thread
#define CHUNK 8           // rows per inner chunk (2 x int4 token loads)

typedef float f32x4 __attribute__((ext_vector_type(4)));
typedef int   i32x4 __attribute__((ext_vector_type(4)));

__device__ __forceinline__ void sincos_fast(float a, float& s, float& c) {
    // Cody-Waite reduction by 2*pi (FMA), then HW transcendental
    // (input in REVOLUTIONS).
    const float INV2PI = 0.15915493667125702f;
    const float PI2_HI = 6.2831854820251465f;
    const float PI2_LO = -1.7484555314695172e-7f;
    float k = rintf(a * INV2PI);               // exact in fp32 (k <= ~2.1e4)
    float r = fmaf(-k, PI2_HI, a);
    r = fmaf(-k, PI2_LO, r);                   // |r| <= pi, err ~4e-7 rad
    float rev = r * INV2PI;
    s = __builtin_amdgcn_sinf(rev);            // v_sin_f32: sin(rev*2pi)
    c = __builtin_amdgcn_cosf(rev);            // v_cos_f32
}

__global__ __launch_bounds__(256) void embed_pe_kernel(
    const int* __restrict__ idx,
    const float* __restrict__ wordlist,
    float* __restrict__ out)
{
    int t  = blockIdx.x * 256 + threadIdx.x;   // 0 .. (L/R)*128 - 1
    int rb = t >> 7;                           // row-group (R rows)
    int cc = t & 127;                          // float4 column
    int i0 = rb * R;

    // Inverse frequencies for pair j0=2cc (cols 4cc,4cc+1), j1=2cc+1.
    const float K = 0.051905126483205076f;     // log2(10000) / 256
    float invf0 = exp2f(-(float)(2 * cc)     * K);
    float invf1 = exp2f(-(float)(2 * cc + 1) * K);

    // Base-row sin/cos (full reduction) + per-row-step rotation.
    float s0, c0, s1, c1, sd0, cd0, sd1, cd1;
    sincos_fast((float)i0 * invf0, s0, c0);
    sincos_fast((float)i0 * invf1, s1, c1);
    sincos_fast(invf0, sd0, cd0);
    sincos_fast(invf1, sd1, cd1);

    // cols 510,511 must be PE=0. (0,0) is a fixed point of the rotation, so
    // zeroing once here suffices -- no per-iteration selects.
    if (cc == VEC_PER_ROW - 1) { s1 = 0.0f; c1 = 0.0f; }

    const i32x4* ip = (const i32x4*)idx + rb * (R / 4);
    const f32x4* wl = (const f32x4*)wordlist;
    f32x4*       op = (f32x4*)out + (size_t)i0 * VEC_PER_ROW + cc;

#pragma unroll
    for (int ch = 0; ch < R / CHUNK; ++ch) {
        // Tokens for this chunk's 8 rows: two int4 loads (wave-uniform addr).
        i32x4 ta = ip[ch * 2];
        i32x4 tb = ip[ch * 2 + 1];
        int tok[CHUNK] = { ta[0], ta[1], ta[2], ta[3],
                           tb[0], tb[1], tb[2], tb[3] };

#pragma unroll
        for (int k = 0; k < CHUNK; ++k) {
            f32x4 w = wl[tok[k] * VEC_PER_ROW + cc];
            f32x4 o;
            o[0] = w[0] + s0;
            o[1] = w[1] + c0;
            o[2] = w[2] + s1;
            o[3] = w[3] + c1;
            op[(size_t)(ch * CHUNK + k) * VEC_PER_ROW] = o;

            // rotate angles forward by one row: (s,c) <- angle + invf
            float ns0 = fmaf(s0, cd0, c0 * sd0);
            float nc0 = fmaf(c0, cd0, -s0 * sd0);
            s0 = ns0; c0 = nc0;
            float ns1 = fmaf(s1, cd1, c1 * sd1);
            float nc1 = fmaf(c1, cd1, -s1 * sd1);
            s1 = ns1; c1 = nc1;
        }
    }
}

extern "C" void kernel_launch(void* const* d_in, const int* in_sizes, int n_in,
                              void* d_out, int out_size, void* d_ws, size_t ws_size,
                              hipStream_t stream) {
    const int*   idx      = (const int*)d_in[0];
    const float* wordlist = (const float*)d_in[1];
    float*       out      = (float*)d_out;

    int total_threads = (L_TOTAL / R) * VEC_PER_ROW;  // 524,288
    int block = 256;
    int grid = total_threads / block;                 // 2,048 blocks
    embed_pe_kernel<<<grid, block, 0, stream>>>(idx, wordlist, out);
}